// Round 13
// baseline (419.032 us; speedup 1.0000x reference)
//
#include <hip/hip_runtime.h>
#include <math.h>

#define BB 2048
#define SS 96
#define DD 7
#define HH 64
#define H2 16
#define FASTR 776  // k_bilstm faS row stride (f16)
#define HST2 72    // k_bilstm h dbuf row stride (f16)
#define LOST2 88   // k_attn loB f16 stride (44 dw % 32 = 12 -> 2-way, free)
#define KST 120    // k_attn qB/tkS/tvT f16 stride (60 dw % 32 = 28 -> 2-way)

typedef _Float16 f16x8 __attribute__((ext_vector_type(8)));
typedef _Float16 f16x4 __attribute__((ext_vector_type(4)));
typedef float f32x4 __attribute__((ext_vector_type(4)));

__device__ __forceinline__ float sigm(float x) { return 1.0f / (1.0f + __expf(-x)); }
__device__ __forceinline__ float tanh_f(float x) { return 1.0f - 2.0f / (__expf(2.0f * x) + 1.0f); }
// load 8 consecutive fp32 (16B-aligned) -> f16x8 fragment
__device__ __forceinline__ f16x8 frag_from_f32(const float* base) {
    const float4* p = (const float4*)base;
    float4 a = p[0], b = p[1];
    f16x8 r;
    r[0] = (_Float16)a.x; r[1] = (_Float16)a.y; r[2] = (_Float16)a.z; r[3] = (_Float16)a.w;
    r[4] = (_Float16)b.x; r[5] = (_Float16)b.y; r[6] = (_Float16)b.z; r[7] = (_Float16)b.w;
    return r;
}

// ---------------- Kernel 1: feature attention (unchanged) ----------------
__global__ __launch_bounds__(256) void k_feat(
    const float* __restrict__ x,
    const float* __restrict__ fv_w, const float* __restrict__ fv_b,
    const float* __restrict__ fk_w, const float* __restrict__ fk_b,
    const float* __restrict__ fq_w, const float* __restrict__ fq_b,
    float* __restrict__ fa_out)
{
    __shared__ float xs[SS * DD], vs[SS * DD], ks[SS * DD], qs[SS * DD];
    __shared__ float att[DD * DD];
    __shared__ float wv[DD * DD], wk[DD * DD], wq[DD * DD];
    __shared__ float bv[DD], bk[DD], bq[DD];
    const int b = blockIdx.x, t = threadIdx.x;
    const float* xb = x + (size_t)b * SS * DD;

    for (int idx = t; idx < SS * DD; idx += 256) xs[idx] = xb[idx];
    if (t < DD * DD) { wv[t] = fv_w[t]; wk[t] = fk_w[t]; wq[t] = fq_w[t]; }
    if (t < DD)      { bv[t] = fv_b[t]; bk[t] = fk_b[t]; bq[t] = fq_b[t]; }
    __syncthreads();

    for (int idx = t; idx < SS * DD; idx += 256) {
        int s = idx / DD, j = idx % DD;
        float a = bv[j];
        #pragma unroll
        for (int i = 0; i < DD; i++) a += xs[s * DD + i] * wv[j * DD + i];
        vs[idx] = a;
    }
    __syncthreads();
    for (int idx = t; idx < SS * DD; idx += 256) {
        int s = idx / DD, j = idx % DD;
        float a = bk[j];
        #pragma unroll
        for (int i = 0; i < DD; i++) a += (xs[s * DD + i] + vs[s * DD + i]) * wk[j * DD + i];
        ks[idx] = a;
    }
    __syncthreads();
    for (int idx = t; idx < SS * DD; idx += 256) {
        int s = idx / DD, j = idx % DD;
        float a = bq[j];
        #pragma unroll
        for (int i = 0; i < DD; i++) a += (xs[s * DD + i] + ks[s * DD + i]) * wq[j * DD + i];
        qs[idx] = a;
    }
    __syncthreads();
    if (t < DD * DD) {
        int i = t / DD, j = t % DD;
        float a = 0.0f;
        for (int s = 0; s < SS; s++) a += qs[s * DD + i] * ks[s * DD + j];
        att[t] = a;
    }
    __syncthreads();
    if (t < DD) {
        float m = -1e30f;
        #pragma unroll
        for (int j = 0; j < DD; j++) m = fmaxf(m, att[t * DD + j]);
        float e[DD]; float sum = 0.0f;
        #pragma unroll
        for (int j = 0; j < DD; j++) { e[j] = __expf(att[t * DD + j] - m); sum += e[j]; }
        float inv = 1.0f / sum;
        #pragma unroll
        for (int j = 0; j < DD; j++) att[t * DD + j] = e[j] * inv;
    }
    __syncthreads();
    for (int idx = t; idx < SS * DD; idx += 256) {
        int s = idx / DD, j = idx % DD;
        float a = xs[idx];
        #pragma unroll
        for (int i = 0; i < DD; i++) a += vs[s * DD + i] * att[i * DD + j];
        fa_out[(size_t)b * SS * DD + idx] = tanh_f(a);
    }
}

// ---------------- Kernel 2: MFMA-batched bidirectional LSTM (unchanged from R12) ----------------
__global__ __launch_bounds__(256, 2) void k_bilstm(
    const float* __restrict__ fa,
    const float* __restrict__ wih_f, const float* __restrict__ whh_f,
    const float* __restrict__ bih_f, const float* __restrict__ bhh_f,
    const float* __restrict__ wih_b, const float* __restrict__ whh_b,
    const float* __restrict__ bih_b, const float* __restrict__ bhh_b,
    _Float16* __restrict__ hf, _Float16* __restrict__ hb)
{
    __shared__ _Float16 faS[16 * FASTR];   // [n][s*8+i], i=7 holds 1.0
    __shared__ _Float16 hS[2][16 * HST2];  // h dbuf: [n][unit]

    const int bx = blockIdx.x;
    const int bg = bx >> 1, dir = bx & 1;
    const int t = threadIdx.x, lane = t & 63, w = t >> 6;
    const int col = lane & 15, quad = lane >> 4;

    const float* wih = dir ? wih_b : wih_f;
    const float* whh = dir ? whh_b : whh_f;
    const float* bih = dir ? bih_b : bih_f;
    const float* bhh = dir ? bhh_b : bhh_f;
    _Float16* hout = dir ? hb : hf;

    for (int i = t; i < 2 * 16 * HST2 / 2; i += 256) ((unsigned int*)hS)[i] = 0u;

    f16x8 wh[4][2];
    f16x8 wi[4];
    #pragma unroll
    for (int gt = 0; gt < 4; gt++) {
        const int row = 16 * (w + 4 * gt) + col;
        wh[gt][0] = frag_from_f32(whh + row * HH + quad * 8);
        wh[gt][1] = frag_from_f32(whh + row * HH + 32 + quad * 8);
        f16x8 v;
        #pragma unroll
        for (int j = 0; j < 8; j++) v[j] = (_Float16)0.0f;
        if (quad == 0) {
            #pragma unroll
            for (int j = 0; j < DD; j++) v[j] = (_Float16)wih[row * DD + j];
            v[7] = (_Float16)(bih[row] + bhh[row]);
        }
        wi[gt] = v;
    }

    const float* fab = fa + (size_t)(bg * 16) * SS * DD;
    for (int idx = t; idx < 16 * SS * DD; idx += 256) {
        int n = idx / (SS * DD), r = idx % (SS * DD);
        int s = r / DD, i = r % DD;
        faS[n * FASTR + s * 8 + i] = (_Float16)fab[idx];
    }
    for (int idx = t; idx < 16 * SS; idx += 256) {
        int n = idx / SS, s = idx % SS;
        faS[n * FASTR + s * 8 + 7] = (_Float16)1.0f;
    }
    __syncthreads();

    const int sstep = dir ? -HH : HH;
    _Float16* hp = hout + ((size_t)(bg * 16 + col)) * SS * HH
                 + (dir ? (SS - 1) : 0) * HH + 16 * w + quad * 4;

    const f32x4 ZC = {0.f, 0.f, 0.f, 0.f};
    float c0 = 0.f, c1 = 0.f, c2 = 0.f, c3 = 0.f;
    f16x4 hq;

    for (int step = 0; step < SS; step++) {
        const int s = dir ? (SS - 1 - step) : step;
        const int p = step & 1;

        if (step) {
            *(f16x4*)hp = hq;
            hp += sstep;
        }

        f16x8 faf;
        #pragma unroll
        for (int j = 0; j < 8; j++) faf[j] = (_Float16)0.0f;
        if (quad == 0) faf = *(const f16x8*)(&faS[col * FASTR + s * 8]);

        f16x8 h0 = *(const f16x8*)(&hS[p][col * HST2 + quad * 8]);
        f16x8 h1 = *(const f16x8*)(&hS[p][col * HST2 + 32 + quad * 8]);

        f32x4 g[4];
        #pragma unroll
        for (int gt = 0; gt < 4; gt++) {
            f32x4 acc = __builtin_amdgcn_mfma_f32_16x16x32_f16(wi[gt], faf, ZC, 0, 0, 0);
            acc = __builtin_amdgcn_mfma_f32_16x16x32_f16(wh[gt][0], h0, acc, 0, 0, 0);
            acc = __builtin_amdgcn_mfma_f32_16x16x32_f16(wh[gt][1], h1, acc, 0, 0, 0);
            g[gt] = acc;
        }
        {
            float iv, fv, gv, ov, hv;
            iv = sigm(g[0][0]); fv = sigm(g[1][0]); gv = tanh_f(g[2][0]); ov = sigm(g[3][0]);
            c0 = fv * c0 + iv * gv; hv = ov * tanh_f(c0); hq[0] = (_Float16)hv;
            iv = sigm(g[0][1]); fv = sigm(g[1][1]); gv = tanh_f(g[2][1]); ov = sigm(g[3][1]);
            c1 = fv * c1 + iv * gv; hv = ov * tanh_f(c1); hq[1] = (_Float16)hv;
            iv = sigm(g[0][2]); fv = sigm(g[1][2]); gv = tanh_f(g[2][2]); ov = sigm(g[3][2]);
            c2 = fv * c2 + iv * gv; hv = ov * tanh_f(c2); hq[2] = (_Float16)hv;
            iv = sigm(g[0][3]); fv = sigm(g[1][3]); gv = tanh_f(g[2][3]); ov = sigm(g[3][3]);
            c3 = fv * c3 + iv * gv; hv = ov * tanh_f(c3); hq[3] = (_Float16)hv;
        }
        *(f16x4*)(&hS[1 - p][col * HST2 + 16 * w + quad * 4]) = hq;
        __syncthreads();
    }
    *(f16x4*)hp = hq;
}

// ---------------- Kernel 3: temporal attention (MFMA f16, unchanged) ----------------
__global__ __launch_bounds__(512, 2) void k_attn(
    const _Float16* __restrict__ hf, const _Float16* __restrict__ hb,
    const float* __restrict__ tv_w, const float* __restrict__ tv_b,
    const float* __restrict__ tk_w, const float* __restrict__ tk_b,
    const float* __restrict__ tq_w, const float* __restrict__ tq_b,
    const float* __restrict__ l2_wih,
    const float* __restrict__ l2_bih, const float* __restrict__ l2_bhh,
    _Float16* __restrict__ xg2)
{
    __shared__ _Float16 loB[SS * LOST2];   // lo -> 'to'
    __shared__ _Float16 qB[SS * KST];      // q[s][f] -> p[s][P]
    __shared__ _Float16 tkS[SS * KST];     // tk[s][f]
    __shared__ _Float16 tvT[HH * KST];     // tv^T[d][P]

    const int b = blockIdx.x, t = threadIdx.x;
    const int lane = t & 63, w = t >> 6;
    const int col = lane & 15, quad = lane >> 4;

    const _Float16* hfp = hf + (size_t)b * SS * HH;
    const _Float16* hbp = hb + (size_t)b * SS * HH;
    for (int g8 = t; g8 < 768; g8 += 512) {
        f16x8 va = *(const f16x8*)(hfp + g8 * 8);
        f16x8 vb = *(const f16x8*)(hbp + g8 * 8);
        int s = g8 >> 3, d = (g8 & 7) * 8;
        f16x8 r;
        #pragma unroll
        for (int j = 0; j < 8; j++) r[j] = (_Float16)(0.5f * ((float)va[j] + (float)vb[j]));
        *(f16x8*)(&loB[s * LOST2 + d]) = r;
    }
    __syncthreads();

    for (int i = 0; i < 9; i++) {
        const int flat = w + 8 * i;
        const int proj = flat / 24, rem = flat % 24;
        const int mt = rem >> 2, nt = rem & 3;
        const float* wmat = (proj == 0) ? tv_w : (proj == 1) ? tk_w : tq_w;
        const float* bvec = (proj == 0) ? tv_b : (proj == 1) ? tk_b : tq_b;
        const int j = 16 * nt + col;
        f32x4 acc = {0.f, 0.f, 0.f, 0.f};
        #pragma unroll
        for (int kc = 0; kc < 2; kc++) {
            f16x8 a  = *(const f16x8*)(&loB[(16 * mt + col) * LOST2 + kc * 32 + quad * 8]);
            f16x8 bb = frag_from_f32(wmat + j * HH + kc * 32 + quad * 8);
            acc = __builtin_amdgcn_mfma_f32_16x16x32_f16(a, bb, acc, 0, 0, 0);
        }
        const float bj = bvec[j];
        #pragma unroll
        for (int r = 0; r < 4; r++) {
            const float v = acc[r] + bj;
            const int row = 16 * mt + quad * 4 + r;
            if (proj == 0)      tvT[j * KST + row] = (_Float16)v;
            else if (proj == 1) tkS[row * KST + j] = (_Float16)v;
            else                qB[row * KST + j]  = (_Float16)v;
        }
    }
    __syncthreads();

    if (w < 6) {
        const int mt = w;
        f16x8 aq0 = *(const f16x8*)(qB + (16 * mt + col) * KST + quad * 8);
        f16x8 aq1 = *(const f16x8*)(qB + (16 * mt + col) * KST + 32 + quad * 8);
        f32x4 sc[6];
        #pragma unroll
        for (int nt = 0; nt < 6; nt++) {
            f32x4 acc = {0.f, 0.f, 0.f, 0.f};
            f16x8 b0 = *(const f16x8*)(tkS + (16 * nt + col) * KST + quad * 8);
            f16x8 b1 = *(const f16x8*)(tkS + (16 * nt + col) * KST + 32 + quad * 8);
            acc = __builtin_amdgcn_mfma_f32_16x16x32_f16(aq0, b0, acc, 0, 0, 0);
            acc = __builtin_amdgcn_mfma_f32_16x16x32_f16(aq1, b1, acc, 0, 0, 0);
            sc[nt] = acc;
        }
        #pragma unroll
        for (int r = 0; r < 4; r++) {
            float m = sc[0][r];
            #pragma unroll
            for (int nt = 1; nt < 6; nt++) m = fmaxf(m, sc[nt][r]);
            #pragma unroll
            for (int o = 1; o < 16; o <<= 1) m = fmaxf(m, __shfl_xor(m, o));
            float e[6]; float sum = 0.0f;
            #pragma unroll
            for (int nt = 0; nt < 6; nt++) { e[nt] = __expf(sc[nt][r] - m); sum += e[nt]; }
            #pragma unroll
            for (int o = 1; o < 16; o <<= 1) sum += __shfl_xor(sum, o);
            const float inv = 1.0f / sum;
            const int row = 16 * mt + quad * 4 + r;
            #pragma unroll
            for (int nt = 0; nt < 6; nt++)
                qB[row * KST + 16 * nt + col] = (_Float16)(e[nt] * inv);
        }
        f16x8 pa0 = *(const f16x8*)(qB + (16 * mt + col) * KST + quad * 8);
        f16x8 pa1 = *(const f16x8*)(qB + (16 * mt + col) * KST + 32 + quad * 8);
        f16x8 pa2 = *(const f16x8*)(qB + (16 * mt + col) * KST + 64 + quad * 8);
        #pragma unroll
        for (int nt = 0; nt < 4; nt++) {
            f32x4 acc = {0.f, 0.f, 0.f, 0.f};
            const _Float16* tvrow = tvT + (16 * nt + col) * KST;
            acc = __builtin_amdgcn_mfma_f32_16x16x32_f16(pa0, *(const f16x8*)(tvrow + quad * 8), acc, 0, 0, 0);
            acc = __builtin_amdgcn_mfma_f32_16x16x32_f16(pa1, *(const f16x8*)(tvrow + 32 + quad * 8), acc, 0, 0, 0);
            acc = __builtin_amdgcn_mfma_f32_16x16x32_f16(pa2, *(const f16x8*)(tvrow + 64 + quad * 8), acc, 0, 0, 0);
            #pragma unroll
            for (int r = 0; r < 4; r++)
                loB[(16 * mt + quad * 4 + r) * LOST2 + 16 * nt + col] = (_Float16)tanh_f(acc[r]);
        }
    }
    __syncthreads();

    for (int i = 0; i < 3; i++) {
        const int flat = w + 8 * i;
        const int mt = flat >> 2, nt = flat & 3;
        const int g = 16 * nt + col;
        f32x4 acc = {0.f, 0.f, 0.f, 0.f};
        #pragma unroll
        for (int kc = 0; kc < 2; kc++) {
            f16x8 a  = *(const f16x8*)(&loB[(16 * mt + col) * LOST2 + kc * 32 + quad * 8]);
            f16x8 bb = frag_from_f32(l2_wih + g * HH + kc * 32 + quad * 8);
            acc = __builtin_amdgcn_mfma_f32_16x16x32_f16(a, bb, acc, 0, 0, 0);
        }
        const float bg2 = l2_bih[g] + l2_bhh[g];
        #pragma unroll
        for (int r = 0; r < 4; r++) {
            const int row = 16 * mt + quad * 4 + r;
            xg2[(size_t)b * SS * HH + row * HH + g] = (_Float16)(acc[r] + bg2);
        }
    }
}

// ---------------- Kernel 4: batched MFMA LSTM2 + fc, ZERO LDS ----------------
// 128 blocks x 64 thr. Per step: 4 MFMA (h recurrence) + nonlin in-lane +
// h transpose via 4 __shfl (no LDS round trip) + fc MFMA + store.
// xg2 gate slices register-prefetched one step ahead (L2-hot).
__global__ __launch_bounds__(64) void k_lstm2(
    const _Float16* __restrict__ xg2,
    const float* __restrict__ l2_whh,
    const float* __restrict__ fc_w, const float* __restrict__ fc_b,
    float* __restrict__ out)
{
    const int bi = blockIdx.x;
    const int bg = bi * 16;
    const int lane = threadIdx.x;
    const int col = lane & 15, quad = lane >> 4;

    // A-frags: whh rows (16mt+col), K=16 real (quads 0-1), pad zero
    f16x8 wa[4];
    #pragma unroll
    for (int mt = 0; mt < 4; mt++) {
        f16x8 v;
        #pragma unroll
        for (int j = 0; j < 8; j++) v[j] = (_Float16)0.0f;
        if (quad < 2) {
            const float* src = l2_whh + (16 * mt + col) * H2 + quad * 8;
            #pragma unroll
            for (int j = 0; j < 8; j++) v[j] = (_Float16)src[j];
        }
        wa[mt] = v;
    }
    f16x8 fca;
    {
        f16x8 v;
        #pragma unroll
        for (int j = 0; j < 8; j++) v[j] = (_Float16)0.0f;
        if (quad < 2 && col < DD) {
            const float* src = fc_w + col * H2 + quad * 8;
            #pragma unroll
            for (int j = 0; j < 8; j++) v[j] = (_Float16)src[j];
        }
        fca = v;
    }
    float fcbr[4];
    #pragma unroll
    for (int r = 0; r < 4; r++) {
        const int d = quad * 4 + r;
        fcbr[r] = (d < DD) ? fc_b[d] : 0.0f;
    }

    const _Float16* xgp = xg2 + (size_t)(bg + col) * SS * HH + 4 * quad;

    float c[4] = {0.f, 0.f, 0.f, 0.f};
    f16x8 hfrag;
    #pragma unroll
    for (int j = 0; j < 8; j++) hfrag[j] = (_Float16)0.0f;

    // prefetch step 0 gates
    f16x4 xi[4];
    #pragma unroll
    for (int mt = 0; mt < 4; mt++) xi[mt] = *(const f16x4*)(xgp + 16 * mt);

    for (int s = 0; s < SS; s++) {
        // prefetch next step's gates (independent; hides L2 latency)
        f16x4 xin[4];
        if (s + 1 < SS) {
            const _Float16* np = xgp + (s + 1) * HH;
            #pragma unroll
            for (int mt = 0; mt < 4; mt++) xin[mt] = *(const f16x4*)(np + 16 * mt);
        }

        f32x4 g[4];
        #pragma unroll
        for (int mt = 0; mt < 4; mt++) {
            f32x4 acc;
            acc[0] = (float)xi[mt][0]; acc[1] = (float)xi[mt][1];
            acc[2] = (float)xi[mt][2]; acc[3] = (float)xi[mt][3];
            g[mt] = __builtin_amdgcn_mfma_f32_16x16x32_f16(wa[mt], hfrag, acc, 0, 0, 0);
        }
        f16x4 hq;
        #pragma unroll
        for (int r = 0; r < 4; r++) {
            float iv = sigm(g[0][r]);
            float fv = sigm(g[1][r]);
            float gv = tanh_f(g[2][r]);
            float ov = sigm(g[3][r]);
            c[r] = fv * c[r] + iv * gv;
            hq[r] = (_Float16)(ov * tanh_f(c[r]));
        }
        // h transpose via shuffles: hfrag[k=8q+j] = h[unit 8q+j][batch col]
        // units 8q..8q+3 live in lane col+32q (its hq), 8q+4..8q+7 in lane col+32q+16
        {
            uint2 pk = *(uint2*)&hq;
            const int s0l = col + 32 * quad;
            const int s1l = s0l + 16;
            unsigned a0 = (unsigned)__shfl((int)pk.x, s0l);
            unsigned a1 = (unsigned)__shfl((int)pk.y, s0l);
            unsigned b0 = (unsigned)__shfl((int)pk.x, s1l);
            unsigned b1 = (unsigned)__shfl((int)pk.y, s1l);
            uint4 packed;
            packed.x = (quad < 2) ? a0 : 0u;
            packed.y = (quad < 2) ? a1 : 0u;
            packed.z = (quad < 2) ? b0 : 0u;
            packed.w = (quad < 2) ? b1 : 0u;
            hfrag = *(f16x8*)&packed;
        }
        // fc (off critical path)
        f32x4 oz = {0.f, 0.f, 0.f, 0.f};
        f32x4 oacc = __builtin_amdgcn_mfma_f32_16x16x32_f16(fca, hfrag, oz, 0, 0, 0);
        float* op = out + ((size_t)(bg + col) * SS + s) * DD;
        #pragma unroll
        for (int r = 0; r < 4; r++) {
            const int d = quad * 4 + r;
            if (d < DD) op[d] = oacc[r] + fcbr[r];
        }

        #pragma unroll
        for (int mt = 0; mt < 4; mt++) xi[mt] = xin[mt];
    }
}

extern "C" void kernel_launch(void* const* d_in, const int* in_sizes, int n_in,
                              void* d_out, int out_size, void* d_ws, size_t ws_size,
                              hipStream_t stream) {
    const float* x     = (const float*)d_in[0];
    const float* fv_w  = (const float*)d_in[1];
    const float* fv_b  = (const float*)d_in[2];
    const float* fk_w  = (const float*)d_in[3];
    const float* fk_b  = (const float*)d_in[4];
    const float* fq_w  = (const float*)d_in[5];
    const float* fq_b  = (const float*)d_in[6];
    const float* l1f_wih = (const float*)d_in[7];
    const float* l1f_whh = (const float*)d_in[8];
    const float* l1f_bih = (const float*)d_in[9];
    const float* l1f_bhh = (const float*)d_in[10];
    const float* l1b_wih = (const float*)d_in[11];
    const float* l1b_whh = (const float*)d_in[12];
    const float* l1b_bih = (const float*)d_in[13];
    const float* l1b_bhh = (const float*)d_in[14];
    const float* tv_w  = (const float*)d_in[15];
    const float* tv_b  = (const float*)d_in[16];
    const float* tk_w  = (const float*)d_in[17];
    const float* tk_b  = (const float*)d_in[18];
    const float* tq_w  = (const float*)d_in[19];
    const float* tq_b  = (const float*)d_in[20];
    const float* l2_wih = (const float*)d_in[21];
    const float* l2_whh = (const float*)d_in[22];
    const float* l2_bih = (const float*)d_in[23];
    const float* l2_bhh = (const float*)d_in[24];
    const float* fc_w  = (const float*)d_in[25];
    const float* fc_b  = (const float*)d_in[26];

    float* fa = (float*)d_ws;                              // B*S*D fp32
    _Float16* hf = (_Float16*)(fa + (size_t)BB * SS * DD); // B*S*H f16
    _Float16* hb = hf + (size_t)BB * SS * HH;              // B*S*H f16
    _Float16* xg2 = hf;  // overlay: k_attn block b reads hf[b] first, writes xg2[b] last

    k_feat<<<BB, 256, 0, stream>>>(x, fv_w, fv_b, fk_w, fk_b, fq_w, fq_b, fa);
    k_bilstm<<<256, 256, 0, stream>>>(fa,
        l1f_wih, l1f_whh, l1f_bih, l1f_bhh,
        l1b_wih, l1b_whh, l1b_bih, l1b_bhh, hf, hb);
    k_attn<<<BB, 512, 0, stream>>>(hf, hb,
        tv_w, tv_b, tk_w, tk_b, tq_w, tq_b,
        l2_wih, l2_bih, l2_bhh, xg2);
    k_lstm2<<<128, 64, 0, stream>>>(xg2, l2_whh, fc_w, fc_b, (float*)d_out);
}

// Round 14
// 403.447 us; speedup vs baseline: 1.0386x; 1.0386x over previous
//
#include <hip/hip_runtime.h>
#include <math.h>

#define BB 2048
#define SS 96
#define DD 7
#define HH 64
#define H2 16
#define FASTR 776  // k_bilstm faS row stride (f16)
#define HST2 72    // k_bilstm h dbuf row stride (f16)
#define LOST2 88   // k_attn loB f16 stride (44 dw % 32 = 12 -> 2-way, free)
#define KST 120    // k_attn qB/tkS/tvT f16 stride (60 dw % 32 = 28 -> 2-way)

typedef _Float16 f16x8 __attribute__((ext_vector_type(8)));
typedef _Float16 f16x4 __attribute__((ext_vector_type(4)));
typedef float f32x4 __attribute__((ext_vector_type(4)));

__device__ __forceinline__ float sigm(float x) { return 1.0f / (1.0f + __expf(-x)); }
__device__ __forceinline__ float tanh_f(float x) { return 1.0f - 2.0f / (__expf(2.0f * x) + 1.0f); }
__device__ __forceinline__ float rl(float v, int l) {
    return __int_as_float(__builtin_amdgcn_readlane(__float_as_int(v), l));
}
// load 8 consecutive fp32 (16B-aligned) -> f16x8 fragment
__device__ __forceinline__ f16x8 frag_from_f32(const float* base) {
    const float4* p = (const float4*)base;
    float4 a = p[0], b = p[1];
    f16x8 r;
    r[0] = (_Float16)a.x; r[1] = (_Float16)a.y; r[2] = (_Float16)a.z; r[3] = (_Float16)a.w;
    r[4] = (_Float16)b.x; r[5] = (_Float16)b.y; r[6] = (_Float16)b.z; r[7] = (_Float16)b.w;
    return r;
}

// ---------------- Kernel 1: feature attention (unchanged) ----------------
__global__ __launch_bounds__(256) void k_feat(
    const float* __restrict__ x,
    const float* __restrict__ fv_w, const float* __restrict__ fv_b,
    const float* __restrict__ fk_w, const float* __restrict__ fk_b,
    const float* __restrict__ fq_w, const float* __restrict__ fq_b,
    float* __restrict__ fa_out)
{
    __shared__ float xs[SS * DD], vs[SS * DD], ks[SS * DD], qs[SS * DD];
    __shared__ float att[DD * DD];
    __shared__ float wv[DD * DD], wk[DD * DD], wq[DD * DD];
    __shared__ float bv[DD], bk[DD], bq[DD];
    const int b = blockIdx.x, t = threadIdx.x;
    const float* xb = x + (size_t)b * SS * DD;

    for (int idx = t; idx < SS * DD; idx += 256) xs[idx] = xb[idx];
    if (t < DD * DD) { wv[t] = fv_w[t]; wk[t] = fk_w[t]; wq[t] = fq_w[t]; }
    if (t < DD)      { bv[t] = fv_b[t]; bk[t] = fk_b[t]; bq[t] = fq_b[t]; }
    __syncthreads();

    for (int idx = t; idx < SS * DD; idx += 256) {
        int s = idx / DD, j = idx % DD;
        float a = bv[j];
        #pragma unroll
        for (int i = 0; i < DD; i++) a += xs[s * DD + i] * wv[j * DD + i];
        vs[idx] = a;
    }
    __syncthreads();
    for (int idx = t; idx < SS * DD; idx += 256) {
        int s = idx / DD, j = idx % DD;
        float a = bk[j];
        #pragma unroll
        for (int i = 0; i < DD; i++) a += (xs[s * DD + i] + vs[s * DD + i]) * wk[j * DD + i];
        ks[idx] = a;
    }
    __syncthreads();
    for (int idx = t; idx < SS * DD; idx += 256) {
        int s = idx / DD, j = idx % DD;
        float a = bq[j];
        #pragma unroll
        for (int i = 0; i < DD; i++) a += (xs[s * DD + i] + ks[s * DD + i]) * wq[j * DD + i];
        qs[idx] = a;
    }
    __syncthreads();
    if (t < DD * DD) {
        int i = t / DD, j = t % DD;
        float a = 0.0f;
        for (int s = 0; s < SS; s++) a += qs[s * DD + i] * ks[s * DD + j];
        att[t] = a;
    }
    __syncthreads();
    if (t < DD) {
        float m = -1e30f;
        #pragma unroll
        for (int j = 0; j < DD; j++) m = fmaxf(m, att[t * DD + j]);
        float e[DD]; float sum = 0.0f;
        #pragma unroll
        for (int j = 0; j < DD; j++) { e[j] = __expf(att[t * DD + j] - m); sum += e[j]; }
        float inv = 1.0f / sum;
        #pragma unroll
        for (int j = 0; j < DD; j++) att[t * DD + j] = e[j] * inv;
    }
    __syncthreads();
    for (int idx = t; idx < SS * DD; idx += 256) {
        int s = idx / DD, j = idx % DD;
        float a = xs[idx];
        #pragma unroll
        for (int i = 0; i < DD; i++) a += vs[s * DD + i] * att[i * DD + j];
        fa_out[(size_t)b * SS * DD + idx] = tanh_f(a);
    }
}

// ---------------- Kernel 2: MFMA-batched bidirectional LSTM (unchanged from R12) ----------------
__global__ __launch_bounds__(256, 2) void k_bilstm(
    const float* __restrict__ fa,
    const float* __restrict__ wih_f, const float* __restrict__ whh_f,
    const float* __restrict__ bih_f, const float* __restrict__ bhh_f,
    const float* __restrict__ wih_b, const float* __restrict__ whh_b,
    const float* __restrict__ bih_b, const float* __restrict__ bhh_b,
    _Float16* __restrict__ hf, _Float16* __restrict__ hb)
{
    __shared__ _Float16 faS[16 * FASTR];   // [n][s*8+i], i=7 holds 1.0
    __shared__ _Float16 hS[2][16 * HST2];  // h dbuf: [n][unit]

    const int bx = blockIdx.x;
    const int bg = bx >> 1, dir = bx & 1;
    const int t = threadIdx.x, lane = t & 63, w = t >> 6;
    const int col = lane & 15, quad = lane >> 4;

    const float* wih = dir ? wih_b : wih_f;
    const float* whh = dir ? whh_b : whh_f;
    const float* bih = dir ? bih_b : bih_f;
    const float* bhh = dir ? bhh_b : bhh_f;
    _Float16* hout = dir ? hb : hf;

    for (int i = t; i < 2 * 16 * HST2 / 2; i += 256) ((unsigned int*)hS)[i] = 0u;

    f16x8 wh[4][2];
    f16x8 wi[4];
    #pragma unroll
    for (int gt = 0; gt < 4; gt++) {
        const int row = 16 * (w + 4 * gt) + col;
        wh[gt][0] = frag_from_f32(whh + row * HH + quad * 8);
        wh[gt][1] = frag_from_f32(whh + row * HH + 32 + quad * 8);
        f16x8 v;
        #pragma unroll
        for (int j = 0; j < 8; j++) v[j] = (_Float16)0.0f;
        if (quad == 0) {
            #pragma unroll
            for (int j = 0; j < DD; j++) v[j] = (_Float16)wih[row * DD + j];
            v[7] = (_Float16)(bih[row] + bhh[row]);
        }
        wi[gt] = v;
    }

    const float* fab = fa + (size_t)(bg * 16) * SS * DD;
    for (int idx = t; idx < 16 * SS * DD; idx += 256) {
        int n = idx / (SS * DD), r = idx % (SS * DD);
        int s = r / DD, i = r % DD;
        faS[n * FASTR + s * 8 + i] = (_Float16)fab[idx];
    }
    for (int idx = t; idx < 16 * SS; idx += 256) {
        int n = idx / SS, s = idx % SS;
        faS[n * FASTR + s * 8 + 7] = (_Float16)1.0f;
    }
    __syncthreads();

    const int sstep = dir ? -HH : HH;
    _Float16* hp = hout + ((size_t)(bg * 16 + col)) * SS * HH
                 + (dir ? (SS - 1) : 0) * HH + 16 * w + quad * 4;

    const f32x4 ZC = {0.f, 0.f, 0.f, 0.f};
    float c0 = 0.f, c1 = 0.f, c2 = 0.f, c3 = 0.f;
    f16x4 hq;

    for (int step = 0; step < SS; step++) {
        const int s = dir ? (SS - 1 - step) : step;
        const int p = step & 1;

        if (step) {
            *(f16x4*)hp = hq;
            hp += sstep;
        }

        f16x8 faf;
        #pragma unroll
        for (int j = 0; j < 8; j++) faf[j] = (_Float16)0.0f;
        if (quad == 0) faf = *(const f16x8*)(&faS[col * FASTR + s * 8]);

        f16x8 h0 = *(const f16x8*)(&hS[p][col * HST2 + quad * 8]);
        f16x8 h1 = *(const f16x8*)(&hS[p][col * HST2 + 32 + quad * 8]);

        f32x4 g[4];
        #pragma unroll
        for (int gt = 0; gt < 4; gt++) {
            f32x4 acc = __builtin_amdgcn_mfma_f32_16x16x32_f16(wi[gt], faf, ZC, 0, 0, 0);
            acc = __builtin_amdgcn_mfma_f32_16x16x32_f16(wh[gt][0], h0, acc, 0, 0, 0);
            acc = __builtin_amdgcn_mfma_f32_16x16x32_f16(wh[gt][1], h1, acc, 0, 0, 0);
            g[gt] = acc;
        }
        {
            float iv, fv, gv, ov, hv;
            iv = sigm(g[0][0]); fv = sigm(g[1][0]); gv = tanh_f(g[2][0]); ov = sigm(g[3][0]);
            c0 = fv * c0 + iv * gv; hv = ov * tanh_f(c0); hq[0] = (_Float16)hv;
            iv = sigm(g[0][1]); fv = sigm(g[1][1]); gv = tanh_f(g[2][1]); ov = sigm(g[3][1]);
            c1 = fv * c1 + iv * gv; hv = ov * tanh_f(c1); hq[1] = (_Float16)hv;
            iv = sigm(g[0][2]); fv = sigm(g[1][2]); gv = tanh_f(g[2][2]); ov = sigm(g[3][2]);
            c2 = fv * c2 + iv * gv; hv = ov * tanh_f(c2); hq[2] = (_Float16)hv;
            iv = sigm(g[0][3]); fv = sigm(g[1][3]); gv = tanh_f(g[2][3]); ov = sigm(g[3][3]);
            c3 = fv * c3 + iv * gv; hv = ov * tanh_f(c3); hq[3] = (_Float16)hv;
        }
        *(f16x4*)(&hS[1 - p][col * HST2 + 16 * w + quad * 4]) = hq;
        __syncthreads();
    }
    *(f16x4*)hp = hq;
}

// ------ Kernel 3: temporal attention + fused LSTM2 scan + fc (MFMA f16) ------
// xg2 stays in LDS (xgS overlays dead tkS); wave 0 runs the 96-step scan
// (readlane dot + shuffle gate exchange, fp32 state); hsb overlays dead tvT;
// 2-wave fc writes out. LDS total unchanged: 78,336 B -> 2 blocks/CU.
__global__ __launch_bounds__(512, 2) void k_attn(
    const _Float16* __restrict__ hf, const _Float16* __restrict__ hb,
    const float* __restrict__ tv_w, const float* __restrict__ tv_b,
    const float* __restrict__ tk_w, const float* __restrict__ tk_b,
    const float* __restrict__ tq_w, const float* __restrict__ tq_b,
    const float* __restrict__ l2_wih, const float* __restrict__ l2_whh,
    const float* __restrict__ l2_bih, const float* __restrict__ l2_bhh,
    const float* __restrict__ fc_w, const float* __restrict__ fc_b,
    float* __restrict__ out)
{
    __shared__ _Float16 loB[SS * LOST2];   // lo -> 'to'
    __shared__ _Float16 qB[SS * KST];      // q[s][f] -> p[s][P]
    __shared__ _Float16 tkS[SS * KST];     // tk[s][f] -> xgS[s][g]
    __shared__ _Float16 tvT[HH * KST];     // tv^T[d][P] -> hsb fp32[96*17]

    const int b = blockIdx.x, t = threadIdx.x;
    const int lane = t & 63, w = t >> 6;
    const int col = lane & 15, quad = lane >> 4;
    _Float16* xgS = tkS;                   // overlay after phase B
    float* hsb = (float*)tvT;              // overlay after phase B

    const _Float16* hfp = hf + (size_t)b * SS * HH;
    const _Float16* hbp = hb + (size_t)b * SS * HH;
    for (int g8 = t; g8 < 768; g8 += 512) {
        f16x8 va = *(const f16x8*)(hfp + g8 * 8);
        f16x8 vb = *(const f16x8*)(hbp + g8 * 8);
        int s = g8 >> 3, d = (g8 & 7) * 8;
        f16x8 r;
        #pragma unroll
        for (int j = 0; j < 8; j++) r[j] = (_Float16)(0.5f * ((float)va[j] + (float)vb[j]));
        *(f16x8*)(&loB[s * LOST2 + d]) = r;
    }
    __syncthreads();

    // ---- projections tv/tk/tq: 72 tile-jobs, 9 per wave ----
    for (int i = 0; i < 9; i++) {
        const int flat = w + 8 * i;
        const int proj = flat / 24, rem = flat % 24;
        const int mt = rem >> 2, nt = rem & 3;
        const float* wmat = (proj == 0) ? tv_w : (proj == 1) ? tk_w : tq_w;
        const float* bvec = (proj == 0) ? tv_b : (proj == 1) ? tk_b : tq_b;
        const int j = 16 * nt + col;
        f32x4 acc = {0.f, 0.f, 0.f, 0.f};
        #pragma unroll
        for (int kc = 0; kc < 2; kc++) {
            f16x8 a  = *(const f16x8*)(&loB[(16 * mt + col) * LOST2 + kc * 32 + quad * 8]);
            f16x8 bb = frag_from_f32(wmat + j * HH + kc * 32 + quad * 8);
            acc = __builtin_amdgcn_mfma_f32_16x16x32_f16(a, bb, acc, 0, 0, 0);
        }
        const float bj = bvec[j];
        #pragma unroll
        for (int r = 0; r < 4; r++) {
            const float v = acc[r] + bj;
            const int row = 16 * mt + quad * 4 + r;
            if (proj == 0)      tvT[j * KST + row] = (_Float16)v;
            else if (proj == 1) tkS[row * KST + j] = (_Float16)v;
            else                qB[row * KST + j]  = (_Float16)v;
        }
    }
    __syncthreads();

    // ---- scores -> softmax -> P -> PV -> 'to' (waves 0..5) ----
    if (w < 6) {
        const int mt = w;
        f16x8 aq0 = *(const f16x8*)(qB + (16 * mt + col) * KST + quad * 8);
        f16x8 aq1 = *(const f16x8*)(qB + (16 * mt + col) * KST + 32 + quad * 8);
        f32x4 sc[6];
        #pragma unroll
        for (int nt = 0; nt < 6; nt++) {
            f32x4 acc = {0.f, 0.f, 0.f, 0.f};
            f16x8 b0 = *(const f16x8*)(tkS + (16 * nt + col) * KST + quad * 8);
            f16x8 b1 = *(const f16x8*)(tkS + (16 * nt + col) * KST + 32 + quad * 8);
            acc = __builtin_amdgcn_mfma_f32_16x16x32_f16(aq0, b0, acc, 0, 0, 0);
            acc = __builtin_amdgcn_mfma_f32_16x16x32_f16(aq1, b1, acc, 0, 0, 0);
            sc[nt] = acc;
        }
        #pragma unroll
        for (int r = 0; r < 4; r++) {
            float m = sc[0][r];
            #pragma unroll
            for (int nt = 1; nt < 6; nt++) m = fmaxf(m, sc[nt][r]);
            #pragma unroll
            for (int o = 1; o < 16; o <<= 1) m = fmaxf(m, __shfl_xor(m, o));
            float e[6]; float sum = 0.0f;
            #pragma unroll
            for (int nt = 0; nt < 6; nt++) { e[nt] = __expf(sc[nt][r] - m); sum += e[nt]; }
            #pragma unroll
            for (int o = 1; o < 16; o <<= 1) sum += __shfl_xor(sum, o);
            const float inv = 1.0f / sum;
            const int row = 16 * mt + quad * 4 + r;
            #pragma unroll
            for (int nt = 0; nt < 6; nt++)
                qB[row * KST + 16 * nt + col] = (_Float16)(e[nt] * inv);
        }
        f16x8 pa0 = *(const f16x8*)(qB + (16 * mt + col) * KST + quad * 8);
        f16x8 pa1 = *(const f16x8*)(qB + (16 * mt + col) * KST + 32 + quad * 8);
        f16x8 pa2 = *(const f16x8*)(qB + (16 * mt + col) * KST + 64 + quad * 8);
        #pragma unroll
        for (int nt = 0; nt < 4; nt++) {
            f32x4 acc = {0.f, 0.f, 0.f, 0.f};
            const _Float16* tvrow = tvT + (16 * nt + col) * KST;
            acc = __builtin_amdgcn_mfma_f32_16x16x32_f16(pa0, *(const f16x8*)(tvrow + quad * 8), acc, 0, 0, 0);
            acc = __builtin_amdgcn_mfma_f32_16x16x32_f16(pa1, *(const f16x8*)(tvrow + 32 + quad * 8), acc, 0, 0, 0);
            acc = __builtin_amdgcn_mfma_f32_16x16x32_f16(pa2, *(const f16x8*)(tvrow + 64 + quad * 8), acc, 0, 0, 0);
            #pragma unroll
            for (int r = 0; r < 4; r++)
                loB[(16 * mt + quad * 4 + r) * LOST2 + 16 * nt + col] = (_Float16)tanh_f(acc[r]);
        }
    }
    __syncthreads();

    // ---- xg2 = to @ l2_wih^T + biases -> LDS xgS (24 tiles, 3 per wave) ----
    for (int i = 0; i < 3; i++) {
        const int flat = w + 8 * i;
        const int mt = flat >> 2, nt = flat & 3;
        const int g = 16 * nt + col;
        f32x4 acc = {0.f, 0.f, 0.f, 0.f};
        #pragma unroll
        for (int kc = 0; kc < 2; kc++) {
            f16x8 a  = *(const f16x8*)(&loB[(16 * mt + col) * LOST2 + kc * 32 + quad * 8]);
            f16x8 bb = frag_from_f32(l2_wih + g * HH + kc * 32 + quad * 8);
            acc = __builtin_amdgcn_mfma_f32_16x16x32_f16(a, bb, acc, 0, 0, 0);
        }
        const float bg2 = l2_bih[g] + l2_bhh[g];
        #pragma unroll
        for (int r = 0; r < 4; r++) {
            const int row = 16 * mt + quad * 4 + r;
            xgS[row * KST + g] = (_Float16)(acc[r] + bg2);
        }
    }
    __syncthreads();

    // ---- LSTM2 scan (wave 0): lane = gate-row (4*16=64); h,c fp32 ----
    if (t < 64) {
        float whr[H2];
        #pragma unroll
        for (int j = 0; j < H2; j++) whr[j] = l2_whh[lane * H2 + j];
        const int myi = lane & 15;
        float h = 0.0f, c = 0.0f;
        for (int s = 0; s < SS; s++) {
            float a = (float)xgS[s * KST + lane];
            #pragma unroll
            for (int j = 0; j < H2; j++) a += rl(h, j) * whr[j];
            float iv = __shfl(a, myi);
            float fv = __shfl(a, H2 + myi);
            float gv = __shfl(a, 2 * H2 + myi);
            float ov = __shfl(a, 3 * H2 + myi);
            c = sigm(fv) * c + sigm(iv) * tanh_f(gv);
            h = sigm(ov) * tanh_f(c);
            if (lane < H2) hsb[s * 17 + lane] = h;
        }
    }
    __syncthreads();

    // ---- fc (waves 0-1) -> out ----
    if (w < 2) {
        const int srow = w * 64 + lane;
        if (srow < SS) {
            float hreg[H2];
            #pragma unroll
            for (int j = 0; j < H2; j++) hreg[j] = hsb[srow * 17 + j];
            float* op = out + (size_t)b * SS * DD + srow * DD;
            for (int d = 0; d < DD; d++) {
                float a = fc_b[d];
                #pragma unroll
                for (int j = 0; j < H2; j++) a += hreg[j] * fc_w[d * H2 + j];
                op[d] = a;
            }
        }
    }
}

extern "C" void kernel_launch(void* const* d_in, const int* in_sizes, int n_in,
                              void* d_out, int out_size, void* d_ws, size_t ws_size,
                              hipStream_t stream) {
    const float* x     = (const float*)d_in[0];
    const float* fv_w  = (const float*)d_in[1];
    const float* fv_b  = (const float*)d_in[2];
    const float* fk_w  = (const float*)d_in[3];
    const float* fk_b  = (const float*)d_in[4];
    const float* fq_w  = (const float*)d_in[5];
    const float* fq_b  = (const float*)d_in[6];
    const float* l1f_wih = (const float*)d_in[7];
    const float* l1f_whh = (const float*)d_in[8];
    const float* l1f_bih = (const float*)d_in[9];
    const float* l1f_bhh = (const float*)d_in[10];
    const float* l1b_wih = (const float*)d_in[11];
    const float* l1b_whh = (const float*)d_in[12];
    const float* l1b_bih = (const float*)d_in[13];
    const float* l1b_bhh = (const float*)d_in[14];
    const float* tv_w  = (const float*)d_in[15];
    const float* tv_b  = (const float*)d_in[16];
    const float* tk_w  = (const float*)d_in[17];
    const float* tk_b  = (const float*)d_in[18];
    const float* tq_w  = (const float*)d_in[19];
    const float* tq_b  = (const float*)d_in[20];
    const float* l2_wih = (const float*)d_in[21];
    const float* l2_whh = (const float*)d_in[22];
    const float* l2_bih = (const float*)d_in[23];
    const float* l2_bhh = (const float*)d_in[24];
    const float* fc_w  = (const float*)d_in[25];
    const float* fc_b  = (const float*)d_in[26];

    float* fa = (float*)d_ws;                              // B*S*D fp32
    _Float16* hf = (_Float16*)(fa + (size_t)BB * SS * DD); // B*S*H f16
    _Float16* hb = hf + (size_t)BB * SS * HH;              // B*S*H f16

    k_feat<<<BB, 256, 0, stream>>>(x, fv_w, fv_b, fk_w, fk_b, fq_w, fq_b, fa);
    k_bilstm<<<256, 256, 0, stream>>>(fa,
        l1f_wih, l1f_whh, l1f_bih, l1f_bhh,
        l1b_wih, l1b_whh, l1b_bih, l1b_bhh, hf, hb);
    k_attn<<<BB, 512, 0, stream>>>(hf, hb,
        tv_w, tv_b, tk_w, tk_b, tq_w, tq_b,
        l2_wih, l2_whh, l2_bih, l2_bhh, fc_w, fc_b,
        (float*)d_out);
}

// Round 15
// 351.699 us; speedup vs baseline: 1.1915x; 1.1471x over previous
//
#include <hip/hip_runtime.h>
#include <math.h>

#define BB 2048
#define SS 96
#define DD 7
#define HH 64
#define H2 16
#define FASTR 776  // k_bilstm faS row stride (f16)
#define HST2 72    // k_bilstm h dbuf row stride (f16)
#define LOST2 88   // k_attn loB f16 stride (44 dw % 32 = 12 -> 2-way, free)
#define KST 120    // k_attn qB/tkS/tvT f16 stride (60 dw % 32 = 28 -> 2-way)
#define HSB 20     // k_lstm2 h-history stride (f16, 40B -> 8B-aligned rows)

typedef _Float16 f16x8 __attribute__((ext_vector_type(8)));
typedef _Float16 f16x4 __attribute__((ext_vector_type(4)));
typedef float f32x4 __attribute__((ext_vector_type(4)));

__device__ __forceinline__ float sigm(float x) { return 1.0f / (1.0f + __expf(-x)); }
__device__ __forceinline__ float tanh_f(float x) { return 1.0f - 2.0f / (__expf(2.0f * x) + 1.0f); }
__device__ __forceinline__ float rl(float v, int l) {
    return __int_as_float(__builtin_amdgcn_readlane(__float_as_int(v), l));
}
// load 8 consecutive fp32 (16B-aligned) -> f16x8 fragment
__device__ __forceinline__ f16x8 frag_from_f32(const float* base) {
    const float4* p = (const float4*)base;
    float4 a = p[0], b = p[1];
    f16x8 r;
    r[0] = (_Float16)a.x; r[1] = (_Float16)a.y; r[2] = (_Float16)a.z; r[3] = (_Float16)a.w;
    r[4] = (_Float16)b.x; r[5] = (_Float16)b.y; r[6] = (_Float16)b.z; r[7] = (_Float16)b.w;
    return r;
}

// ---------------- Kernel 1: feature attention (unchanged) ----------------
__global__ __launch_bounds__(256) void k_feat(
    const float* __restrict__ x,
    const float* __restrict__ fv_w, const float* __restrict__ fv_b,
    const float* __restrict__ fk_w, const float* __restrict__ fk_b,
    const float* __restrict__ fq_w, const float* __restrict__ fq_b,
    float* __restrict__ fa_out)
{
    __shared__ float xs[SS * DD], vs[SS * DD], ks[SS * DD], qs[SS * DD];
    __shared__ float att[DD * DD];
    __shared__ float wv[DD * DD], wk[DD * DD], wq[DD * DD];
    __shared__ float bv[DD], bk[DD], bq[DD];
    const int b = blockIdx.x, t = threadIdx.x;
    const float* xb = x + (size_t)b * SS * DD;

    for (int idx = t; idx < SS * DD; idx += 256) xs[idx] = xb[idx];
    if (t < DD * DD) { wv[t] = fv_w[t]; wk[t] = fk_w[t]; wq[t] = fq_w[t]; }
    if (t < DD)      { bv[t] = fv_b[t]; bk[t] = fk_b[t]; bq[t] = fq_b[t]; }
    __syncthreads();

    for (int idx = t; idx < SS * DD; idx += 256) {
        int s = idx / DD, j = idx % DD;
        float a = bv[j];
        #pragma unroll
        for (int i = 0; i < DD; i++) a += xs[s * DD + i] * wv[j * DD + i];
        vs[idx] = a;
    }
    __syncthreads();
    for (int idx = t; idx < SS * DD; idx += 256) {
        int s = idx / DD, j = idx % DD;
        float a = bk[j];
        #pragma unroll
        for (int i = 0; i < DD; i++) a += (xs[s * DD + i] + vs[s * DD + i]) * wk[j * DD + i];
        ks[idx] = a;
    }
    __syncthreads();
    for (int idx = t; idx < SS * DD; idx += 256) {
        int s = idx / DD, j = idx % DD;
        float a = bq[j];
        #pragma unroll
        for (int i = 0; i < DD; i++) a += (xs[s * DD + i] + ks[s * DD + i]) * wq[j * DD + i];
        qs[idx] = a;
    }
    __syncthreads();
    if (t < DD * DD) {
        int i = t / DD, j = t % DD;
        float a = 0.0f;
        for (int s = 0; s < SS; s++) a += qs[s * DD + i] * ks[s * DD + j];
        att[t] = a;
    }
    __syncthreads();
    if (t < DD) {
        float m = -1e30f;
        #pragma unroll
        for (int j = 0; j < DD; j++) m = fmaxf(m, att[t * DD + j]);
        float e[DD]; float sum = 0.0f;
        #pragma unroll
        for (int j = 0; j < DD; j++) { e[j] = __expf(att[t * DD + j] - m); sum += e[j]; }
        float inv = 1.0f / sum;
        #pragma unroll
        for (int j = 0; j < DD; j++) att[t * DD + j] = e[j] * inv;
    }
    __syncthreads();
    for (int idx = t; idx < SS * DD; idx += 256) {
        int s = idx / DD, j = idx % DD;
        float a = xs[idx];
        #pragma unroll
        for (int i = 0; i < DD; i++) a += vs[s * DD + i] * att[i * DD + j];
        fa_out[(size_t)b * SS * DD + idx] = tanh_f(a);
    }
}

// ---------------- Kernel 2: MFMA-batched bidirectional LSTM (unchanged from R12) ----------------
__global__ __launch_bounds__(256, 2) void k_bilstm(
    const float* __restrict__ fa,
    const float* __restrict__ wih_f, const float* __restrict__ whh_f,
    const float* __restrict__ bih_f, const float* __restrict__ bhh_f,
    const float* __restrict__ wih_b, const float* __restrict__ whh_b,
    const float* __restrict__ bih_b, const float* __restrict__ bhh_b,
    _Float16* __restrict__ hf, _Float16* __restrict__ hb)
{
    __shared__ _Float16 faS[16 * FASTR];   // [n][s*8+i], i=7 holds 1.0
    __shared__ _Float16 hS[2][16 * HST2];  // h dbuf: [n][unit]

    const int bx = blockIdx.x;
    const int bg = bx >> 1, dir = bx & 1;
    const int t = threadIdx.x, lane = t & 63, w = t >> 6;
    const int col = lane & 15, quad = lane >> 4;

    const float* wih = dir ? wih_b : wih_f;
    const float* whh = dir ? whh_b : whh_f;
    const float* bih = dir ? bih_b : bih_f;
    const float* bhh = dir ? bhh_b : bhh_f;
    _Float16* hout = dir ? hb : hf;

    for (int i = t; i < 2 * 16 * HST2 / 2; i += 256) ((unsigned int*)hS)[i] = 0u;

    f16x8 wh[4][2];
    f16x8 wi[4];
    #pragma unroll
    for (int gt = 0; gt < 4; gt++) {
        const int row = 16 * (w + 4 * gt) + col;
        wh[gt][0] = frag_from_f32(whh + row * HH + quad * 8);
        wh[gt][1] = frag_from_f32(whh + row * HH + 32 + quad * 8);
        f16x8 v;
        #pragma unroll
        for (int j = 0; j < 8; j++) v[j] = (_Float16)0.0f;
        if (quad == 0) {
            #pragma unroll
            for (int j = 0; j < DD; j++) v[j] = (_Float16)wih[row * DD + j];
            v[7] = (_Float16)(bih[row] + bhh[row]);
        }
        wi[gt] = v;
    }

    const float* fab = fa + (size_t)(bg * 16) * SS * DD;
    for (int idx = t; idx < 16 * SS * DD; idx += 256) {
        int n = idx / (SS * DD), r = idx % (SS * DD);
        int s = r / DD, i = r % DD;
        faS[n * FASTR + s * 8 + i] = (_Float16)fab[idx];
    }
    for (int idx = t; idx < 16 * SS; idx += 256) {
        int n = idx / SS, s = idx % SS;
        faS[n * FASTR + s * 8 + 7] = (_Float16)1.0f;
    }
    __syncthreads();

    const int sstep = dir ? -HH : HH;
    _Float16* hp = hout + ((size_t)(bg * 16 + col)) * SS * HH
                 + (dir ? (SS - 1) : 0) * HH + 16 * w + quad * 4;

    const f32x4 ZC = {0.f, 0.f, 0.f, 0.f};
    float c0 = 0.f, c1 = 0.f, c2 = 0.f, c3 = 0.f;
    f16x4 hq;

    for (int step = 0; step < SS; step++) {
        const int s = dir ? (SS - 1 - step) : step;
        const int p = step & 1;

        if (step) {
            *(f16x4*)hp = hq;
            hp += sstep;
        }

        f16x8 faf;
        #pragma unroll
        for (int j = 0; j < 8; j++) faf[j] = (_Float16)0.0f;
        if (quad == 0) faf = *(const f16x8*)(&faS[col * FASTR + s * 8]);

        f16x8 h0 = *(const f16x8*)(&hS[p][col * HST2 + quad * 8]);
        f16x8 h1 = *(const f16x8*)(&hS[p][col * HST2 + 32 + quad * 8]);

        f32x4 g[4];
        #pragma unroll
        for (int gt = 0; gt < 4; gt++) {
            f32x4 acc = __builtin_amdgcn_mfma_f32_16x16x32_f16(wi[gt], faf, ZC, 0, 0, 0);
            acc = __builtin_amdgcn_mfma_f32_16x16x32_f16(wh[gt][0], h0, acc, 0, 0, 0);
            acc = __builtin_amdgcn_mfma_f32_16x16x32_f16(wh[gt][1], h1, acc, 0, 0, 0);
            g[gt] = acc;
        }
        {
            float iv, fv, gv, ov, hv;
            iv = sigm(g[0][0]); fv = sigm(g[1][0]); gv = tanh_f(g[2][0]); ov = sigm(g[3][0]);
            c0 = fv * c0 + iv * gv; hv = ov * tanh_f(c0); hq[0] = (_Float16)hv;
            iv = sigm(g[0][1]); fv = sigm(g[1][1]); gv = tanh_f(g[2][1]); ov = sigm(g[3][1]);
            c1 = fv * c1 + iv * gv; hv = ov * tanh_f(c1); hq[1] = (_Float16)hv;
            iv = sigm(g[0][2]); fv = sigm(g[1][2]); gv = tanh_f(g[2][2]); ov = sigm(g[3][2]);
            c2 = fv * c2 + iv * gv; hv = ov * tanh_f(c2); hq[2] = (_Float16)hv;
            iv = sigm(g[0][3]); fv = sigm(g[1][3]); gv = tanh_f(g[2][3]); ov = sigm(g[3][3]);
            c3 = fv * c3 + iv * gv; hv = ov * tanh_f(c3); hq[3] = (_Float16)hv;
        }
        *(f16x4*)(&hS[1 - p][col * HST2 + 16 * w + quad * 4]) = hq;
        __syncthreads();
    }
    *(f16x4*)hp = hq;
}

// ---------------- Kernel 3: temporal attention (MFMA f16, R12 version) ----------------
// Writes xg2 (f16, [b][s][64]) to global — overlaid on hf region (block-local WAR, safe).
__global__ __launch_bounds__(512, 2) void k_attn(
    const _Float16* __restrict__ hf, const _Float16* __restrict__ hb,
    const float* __restrict__ tv_w, const float* __restrict__ tv_b,
    const float* __restrict__ tk_w, const float* __restrict__ tk_b,
    const float* __restrict__ tq_w, const float* __restrict__ tq_b,
    const float* __restrict__ l2_wih,
    const float* __restrict__ l2_bih, const float* __restrict__ l2_bhh,
    _Float16* __restrict__ xg2)
{
    __shared__ _Float16 loB[SS * LOST2];   // lo -> 'to'
    __shared__ _Float16 qB[SS * KST];      // q[s][f] -> p[s][P]
    __shared__ _Float16 tkS[SS * KST];     // tk[s][f]
    __shared__ _Float16 tvT[HH * KST];     // tv^T[d][P]

    const int b = blockIdx.x, t = threadIdx.x;
    const int lane = t & 63, w = t >> 6;
    const int col = lane & 15, quad = lane >> 4;

    const _Float16* hfp = hf + (size_t)b * SS * HH;
    const _Float16* hbp = hb + (size_t)b * SS * HH;
    for (int g8 = t; g8 < 768; g8 += 512) {
        f16x8 va = *(const f16x8*)(hfp + g8 * 8);
        f16x8 vb = *(const f16x8*)(hbp + g8 * 8);
        int s = g8 >> 3, d = (g8 & 7) * 8;
        f16x8 r;
        #pragma unroll
        for (int j = 0; j < 8; j++) r[j] = (_Float16)(0.5f * ((float)va[j] + (float)vb[j]));
        *(f16x8*)(&loB[s * LOST2 + d]) = r;
    }
    __syncthreads();

    for (int i = 0; i < 9; i++) {
        const int flat = w + 8 * i;
        const int proj = flat / 24, rem = flat % 24;
        const int mt = rem >> 2, nt = rem & 3;
        const float* wmat = (proj == 0) ? tv_w : (proj == 1) ? tk_w : tq_w;
        const float* bvec = (proj == 0) ? tv_b : (proj == 1) ? tk_b : tq_b;
        const int j = 16 * nt + col;
        f32x4 acc = {0.f, 0.f, 0.f, 0.f};
        #pragma unroll
        for (int kc = 0; kc < 2; kc++) {
            f16x8 a  = *(const f16x8*)(&loB[(16 * mt + col) * LOST2 + kc * 32 + quad * 8]);
            f16x8 bb = frag_from_f32(wmat + j * HH + kc * 32 + quad * 8);
            acc = __builtin_amdgcn_mfma_f32_16x16x32_f16(a, bb, acc, 0, 0, 0);
        }
        const float bj = bvec[j];
        #pragma unroll
        for (int r = 0; r < 4; r++) {
            const float v = acc[r] + bj;
            const int row = 16 * mt + quad * 4 + r;
            if (proj == 0)      tvT[j * KST + row] = (_Float16)v;
            else if (proj == 1) tkS[row * KST + j] = (_Float16)v;
            else                qB[row * KST + j]  = (_Float16)v;
        }
    }
    __syncthreads();

    if (w < 6) {
        const int mt = w;
        f16x8 aq0 = *(const f16x8*)(qB + (16 * mt + col) * KST + quad * 8);
        f16x8 aq1 = *(const f16x8*)(qB + (16 * mt + col) * KST + 32 + quad * 8);
        f32x4 sc[6];
        #pragma unroll
        for (int nt = 0; nt < 6; nt++) {
            f32x4 acc = {0.f, 0.f, 0.f, 0.f};
            f16x8 b0 = *(const f16x8*)(tkS + (16 * nt + col) * KST + quad * 8);
            f16x8 b1 = *(const f16x8*)(tkS + (16 * nt + col) * KST + 32 + quad * 8);
            acc = __builtin_amdgcn_mfma_f32_16x16x32_f16(aq0, b0, acc, 0, 0, 0);
            acc = __builtin_amdgcn_mfma_f32_16x16x32_f16(aq1, b1, acc, 0, 0, 0);
            sc[nt] = acc;
        }
        #pragma unroll
        for (int r = 0; r < 4; r++) {
            float m = sc[0][r];
            #pragma unroll
            for (int nt = 1; nt < 6; nt++) m = fmaxf(m, sc[nt][r]);
            #pragma unroll
            for (int o = 1; o < 16; o <<= 1) m = fmaxf(m, __shfl_xor(m, o));
            float e[6]; float sum = 0.0f;
            #pragma unroll
            for (int nt = 0; nt < 6; nt++) { e[nt] = __expf(sc[nt][r] - m); sum += e[nt]; }
            #pragma unroll
            for (int o = 1; o < 16; o <<= 1) sum += __shfl_xor(sum, o);
            const float inv = 1.0f / sum;
            const int row = 16 * mt + quad * 4 + r;
            #pragma unroll
            for (int nt = 0; nt < 6; nt++)
                qB[row * KST + 16 * nt + col] = (_Float16)(e[nt] * inv);
        }
        f16x8 pa0 = *(const f16x8*)(qB + (16 * mt + col) * KST + quad * 8);
        f16x8 pa1 = *(const f16x8*)(qB + (16 * mt + col) * KST + 32 + quad * 8);
        f16x8 pa2 = *(const f16x8*)(qB + (16 * mt + col) * KST + 64 + quad * 8);
        #pragma unroll
        for (int nt = 0; nt < 4; nt++) {
            f32x4 acc = {0.f, 0.f, 0.f, 0.f};
            const _Float16* tvrow = tvT + (16 * nt + col) * KST;
            acc = __builtin_amdgcn_mfma_f32_16x16x32_f16(pa0, *(const f16x8*)(tvrow + quad * 8), acc, 0, 0, 0);
            acc = __builtin_amdgcn_mfma_f32_16x16x32_f16(pa1, *(const f16x8*)(tvrow + 32 + quad * 8), acc, 0, 0, 0);
            acc = __builtin_amdgcn_mfma_f32_16x16x32_f16(pa2, *(const f16x8*)(tvrow + 64 + quad * 8), acc, 0, 0, 0);
            #pragma unroll
            for (int r = 0; r < 4; r++)
                loB[(16 * mt + quad * 4 + r) * LOST2 + 16 * nt + col] = (_Float16)tanh_f(acc[r]);
        }
    }
    __syncthreads();

    for (int i = 0; i < 3; i++) {
        const int flat = w + 8 * i;
        const int mt = flat >> 2, nt = flat & 3;
        const int g = 16 * nt + col;
        f32x4 acc = {0.f, 0.f, 0.f, 0.f};
        #pragma unroll
        for (int kc = 0; kc < 2; kc++) {
            f16x8 a  = *(const f16x8*)(&loB[(16 * mt + col) * LOST2 + kc * 32 + quad * 8]);
            f16x8 bb = frag_from_f32(l2_wih + g * HH + kc * 32 + quad * 8);
            acc = __builtin_amdgcn_mfma_f32_16x16x32_f16(a, bb, acc, 0, 0, 0);
        }
        const float bg2 = l2_bih[g] + l2_bhh[g];
        #pragma unroll
        for (int r = 0; r < 4; r++) {
            const int row = 16 * mt + quad * 4 + r;
            xg2[(size_t)b * SS * HH + row * HH + g] = (_Float16)(acc[r] + bg2);
        }
    }
}

// ---------------- Kernel 4: LSTM2 + fc, one batch per WAVE ----------------
// 512 blocks x 256 thr (4 waves); wave w owns batch blockIdx.x*4+w.
// lane = gate-row (4 gates x 16 units). 16 readlane+fma per step; gate
// exchange via 4 __shfl; xg2 loads register-prefetched one step ahead.
__global__ __launch_bounds__(256) void k_lstm2(
    const _Float16* __restrict__ xg2,
    const float* __restrict__ l2_whh,
    const float* __restrict__ fc_w, const float* __restrict__ fc_b,
    float* __restrict__ out)
{
    __shared__ _Float16 hsb[4][SS * HSB];

    const int t = threadIdx.x, lane = t & 63, w = t >> 6;
    const int n = blockIdx.x * 4 + w;
    const int u16 = lane & 15;

    float whr[H2];
    #pragma unroll
    for (int j = 0; j < H2; j++) whr[j] = l2_whh[lane * H2 + j];

    const _Float16* xgp = xg2 + (size_t)n * SS * HH + lane;
    float h = 0.0f, c = 0.0f;
    _Float16 xv = xgp[0];

    for (int s = 0; s < SS; s++) {
        _Float16 xnext = (_Float16)0.0f;
        if (s + 1 < SS) xnext = xgp[(s + 1) * HH];   // prefetch (L2-hot)

        float a = (float)xv;
        #pragma unroll
        for (int j = 0; j < H2; j++) a += rl(h, j) * whr[j];
        float iv = __shfl(a, u16);
        float fv = __shfl(a, H2 + u16);
        float gv = __shfl(a, 2 * H2 + u16);
        float ov = __shfl(a, 3 * H2 + u16);
        c = sigm(fv) * c + sigm(iv) * tanh_f(gv);
        h = sigm(ov) * tanh_f(c);
        if (lane < H2) hsb[w][s * HSB + lane] = (_Float16)h;
        xv = xnext;
    }
    __syncthreads();

    // fc: lane handles rows s = lane, lane+64
    for (int s = lane; s < SS; s += 64) {
        float hr[H2];
        #pragma unroll
        for (int j = 0; j < H2; j++) hr[j] = (float)hsb[w][s * HSB + j];
        float* op = out + ((size_t)n * SS + s) * DD;
        #pragma unroll
        for (int d = 0; d < DD; d++) {
            float a = fc_b[d];
            #pragma unroll
            for (int j = 0; j < H2; j++) a += hr[j] * fc_w[d * H2 + j];
            op[d] = a;
        }
    }
}

extern "C" void kernel_launch(void* const* d_in, const int* in_sizes, int n_in,
                              void* d_out, int out_size, void* d_ws, size_t ws_size,
                              hipStream_t stream) {
    const float* x     = (const float*)d_in[0];
    const float* fv_w  = (const float*)d_in[1];
    const float* fv_b  = (const float*)d_in[2];
    const float* fk_w  = (const float*)d_in[3];
    const float* fk_b  = (const float*)d_in[4];
    const float* fq_w  = (const float*)d_in[5];
    const float* fq_b  = (const float*)d_in[6];
    const float* l1f_wih = (const float*)d_in[7];
    const float* l1f_whh = (const float*)d_in[8];
    const float* l1f_bih = (const float*)d_in[9];
    const float* l1f_bhh = (const float*)d_in[10];
    const float* l1b_wih = (const float*)d_in[11];
    const float* l1b_whh = (const float*)d_in[12];
    const float* l1b_bih = (const float*)d_in[13];
    const float* l1b_bhh = (const float*)d_in[14];
    const float* tv_w  = (const float*)d_in[15];
    const float* tv_b  = (const float*)d_in[16];
    const float* tk_w  = (const float*)d_in[17];
    const float* tk_b  = (const float*)d_in[18];
    const float* tq_w  = (const float*)d_in[19];
    const float* tq_b  = (const float*)d_in[20];
    const float* l2_wih = (const float*)d_in[21];
    const float* l2_whh = (const float*)d_in[22];
    const float* l2_bih = (const float*)d_in[23];
    const float* l2_bhh = (const float*)d_in[24];
    const float* fc_w  = (const float*)d_in[25];
    const float* fc_b  = (const float*)d_in[26];

    float* fa = (float*)d_ws;                              // B*S*D fp32
    _Float16* hf = (_Float16*)(fa + (size_t)BB * SS * DD); // B*S*H f16
    _Float16* hb = hf + (size_t)BB * SS * HH;              // B*S*H f16
    _Float16* xg2 = hf;  // overlay: k_attn block b reads hf[b] first, writes xg2[b] last

    k_feat<<<BB, 256, 0, stream>>>(x, fv_w, fv_b, fk_w, fk_b, fq_w, fq_b, fa);
    k_bilstm<<<256, 256, 0, stream>>>(fa,
        l1f_wih, l1f_whh, l1f_bih, l1f_bhh,
        l1b_wih, l1b_whh, l1b_bih, l1b_bhh, hf, hb);
    k_attn<<<BB, 512, 0, stream>>>(hf, hb,
        tv_w, tv_b, tk_w, tk_b, tq_w, tq_b,
        l2_wih, l2_bih, l2_bhh, xg2);
    k_lstm2<<<512, 256, 0, stream>>>(xg2, l2_whh, fc_w, fc_b, (float*)d_out);
}